// Round 4
// baseline (388.072 us; speedup 1.0000x reference)
//
#include <hip/hip_runtime.h>
#include <cstdint>
#include <cstddef>

typedef unsigned short u16;
typedef unsigned int   u32;

typedef __bf16 bf16x8 __attribute__((ext_vector_type(8)));
typedef float  f32x4  __attribute__((ext_vector_type(4)));

#define NROWS 4096
#define INF   512
#define OUTF  512
#define EMB   64
#define MHID  128
#define DB    9
#define KDIM  (INF * DB)   /* 4608 */
#define MN    (NROWS * OUTF)   /* 2097152 */

__device__ __forceinline__ u16 f2bf(float f) {
    union { float f; u32 ui; } v; v.f = f;
    u32 u = v.ui;
    u += 0x7fffu + ((u >> 16) & 1u);   // RTNE
    return (u16)(u >> 16);
}
__device__ __forceinline__ float gridv(int t) { return (float)(t - 3) * 0.4f - 1.0f; }

// ---------------- kernel 1: meff — one wave per output ----------------
// outputs per layer: 576 Meff[j,d] + 9 c[d].  Mc layout: [layer*1024 + o]
__global__ __launch_bounds__(256) void meff_kernel(
    const float* __restrict__ w1_0, const float* __restrict__ b1_0,
    const float* __restrict__ w2_0, const float* __restrict__ b2_0,
    const float* __restrict__ w1_1, const float* __restrict__ b1_1,
    const float* __restrict__ w2_1, const float* __restrict__ b2_1,
    float* __restrict__ Mc)
{
    int tid  = threadIdx.x;
    int lane = tid & 63;
    int wid  = blockIdx.x * 4 + (tid >> 6);
    if (wid >= 1170) return;
    int layer = wid / 585;
    int o     = wid % 585;
    const float* w1 = layer ? w1_1 : w1_0;
    const float* b1 = layer ? b1_1 : b1_0;
    const float* w2 = layer ? w2_1 : w2_0;
    const float* b2 = layer ? b2_1 : b2_0;

    float p;
    int d;
    if (o < 576) {
        int j = o / 9; d = o % 9;
        p = w1[lane * EMB + j]        * w2[d * MHID + lane]
          + w1[(lane + 64) * EMB + j] * w2[d * MHID + lane + 64];
    } else {
        d = o - 576;
        p = b1[lane] * w2[d * MHID + lane] + b1[lane + 64] * w2[d * MHID + lane + 64];
    }
#pragma unroll
    for (int off = 32; off >= 1; off >>= 1)
        p += __shfl_xor(p, off, 64);
    if (lane == 0) {
        if (o >= 576) p += b2[d];
        Mc[layer * 1024 + o] = p;
    }
}

// ---------------- kernel 2: genw v2 — 4 rows/thread, Ms broadcast, no tile ------
// Bw[e*9+d] = bf16( emb[e,:]*Meff[:,d] + c[d] ).  grid (256, 2-layers) x 256 thr.
__global__ __launch_bounds__(256) void genw_kernel(
    const float* __restrict__ emb0, const float* __restrict__ emb1,
    const float* __restrict__ Mc,
    u16* __restrict__ Bw0, u16* __restrict__ Bw1)
{
    __shared__ float Ms[64 * 12];                 // 3072 B, padded rows of 12
    __shared__ float Cs[9];
    __shared__ __align__(16) u16 ob[1024 * 9];    // 18432 B out-stage

    int layer = blockIdx.y;
    const float* emb = layer ? emb1 : emb0;
    u16* Bw = layer ? Bw1 : Bw0;
    const float* mc = Mc + layer * 1024;

    int tid = threadIdx.x;
    for (int idx = tid; idx < 585; idx += 256) {
        float v = mc[idx];
        if (idx < 576) Ms[(idx / 9) * 12 + (idx % 9)] = v;
        else Cs[idx - 576] = v;
    }
    __syncthreads();

    size_t rowbase = (size_t)blockIdx.x * 1024;   // 1024 rows per block
    float acc[4][9];
#pragma unroll
    for (int r = 0; r < 4; ++r)
#pragma unroll
        for (int d = 0; d < 9; ++d) acc[r][d] = Cs[d];

    const float4* g4 = (const float4*)(emb + rowbase * EMB);
#pragma unroll
    for (int jj = 0; jj < 16; ++jj) {
        float vv[4][4];
#pragma unroll
        for (int r = 0; r < 4; ++r)
            *(float4*)vv[r] = g4[(size_t)(r * 256 + tid) * 16 + jj];
#pragma unroll
        for (int t = 0; t < 4; ++t) {
            const float* m = &Ms[(jj * 4 + t) * 12];
#pragma unroll
            for (int d = 0; d < 9; ++d) {
                float mv = m[d];                  // wave-uniform LDS broadcast
                acc[0][d] += vv[0][t] * mv;
                acc[1][d] += vv[1][t] * mv;
                acc[2][d] += vv[2][t] * mv;
                acc[3][d] += vv[3][t] * mv;
            }
        }
    }

#pragma unroll
    for (int r = 0; r < 4; ++r)
#pragma unroll
        for (int d = 0; d < 9; ++d)
            ob[(r * 256 + tid) * 9 + d] = f2bf(acc[r][d]);
    __syncthreads();

    const uint4* src = (const uint4*)ob;          // 1152 uint4
    uint4* dst = (uint4*)(Bw + rowbase * 9);      // blk*18432 B, 16B aligned
    for (int s = tid; s < 1152; s += 256) dst[s] = src[s];
}

// ---------------- kernel 3: phi (optionally fused split-K reduce) ----------------
__global__ __launch_bounds__(256) void phi_kernel(const float* __restrict__ xin,
                                                  const float* __restrict__ part,
                                                  int S,
                                                  u16* __restrict__ phi)
{
    __shared__ __align__(16) u16 lbuf[256 * 9];   // 4608 B
    int tid = threadIdx.x;
    int idx = blockIdx.x * 256 + tid;

    float xv;
    if (part) {
        xv = 0.f;
        for (int z = 0; z < S; ++z) xv += part[(size_t)z * MN + idx];
    } else {
        xv = xin[idx];
    }

    float b[11];
#pragma unroll
    for (int t = 0; t < 11; ++t)
        b[t] = (xv >= gridv(t) && xv < gridv(t + 1)) ? 1.0f : 0.0f;
#pragma unroll
    for (int k = 1; k <= 3; ++k) {
#pragma unroll
        for (int t = 0; t + k < 11; ++t) {
            float dp = (gridv(t + k) - gridv(t)) + 1e-8f;
            float dn = (gridv(t + k + 1) - gridv(t + 1)) + 1e-8f;
            b[t] = (xv - gridv(t)) / dp * b[t] + (gridv(t + k + 1) - xv) / dn * b[t + 1];
        }
    }
    float sil = xv / (1.0f + expf(-xv));

#pragma unroll
    for (int d = 0; d < 8; ++d) lbuf[tid * 9 + d] = f2bf(b[d]);
    lbuf[tid * 9 + 8] = f2bf(sil);
    __syncthreads();

    const uint4* src = (const uint4*)lbuf;        // 288 uint4
    uint4* dst = (uint4*)(phi + (size_t)blockIdx.x * 256 * 9);
    for (int s = tid; s < 288; s += 256) dst[s] = src[s];
}

// ---------------- kernel 4: split-K GEMM  Cpart[z] = A[:,kz] * B[:,kz]^T ----------
#define GLOAD16(gp, lp) __builtin_amdgcn_global_load_lds(                         \
    (const __attribute__((address_space(1))) u32*)(gp),                           \
    (__attribute__((address_space(3))) u32*)(lp), 16, 0, 0)

__global__ __launch_bounds__(256, 4) void gemm_kernel(const __bf16* __restrict__ A,
                                                      const __bf16* __restrict__ B,
                                                      float* __restrict__ Cpart,
                                                      int N, int K, int ksz)
{
    __shared__ __align__(16) __bf16 As[128 * 64];
    __shared__ __align__(16) __bf16 Bs[128 * 64];

    int tid  = threadIdx.x;
    int lane = tid & 63;
    int wv   = tid >> 6;
    int wm   = wv >> 1, wn = wv & 1;
    int brow = blockIdx.x * 128;
    int bcol = blockIdx.y * 128;
    int z    = blockIdx.z;
    int kbeg = z * ksz, kend = kbeg + ksz;

    f32x4 acc[4][4];
#pragma unroll
    for (int r = 0; r < 4; ++r)
#pragma unroll
        for (int c = 0; c < 4; ++c)
#pragma unroll
            for (int g = 0; g < 4; ++g) acc[r][c][g] = 0.0f;

    int quad = lane >> 4;
    int l16  = lane & 15;

    for (int k0 = kbeg; k0 < kend; k0 += 64) {
#pragma unroll
        for (int q = 0; q < 4; ++q) {
            int chunk = q * 256 + wv * 64 + lane;    // 0..1023 16B-chunks
            int row   = chunk >> 3;
            int slot  = chunk & 7;
            int col   = ((slot ^ (row & 7)) << 3);   // XOR swizzle (0 conflicts, R2)
            const __bf16* ga = A + (size_t)(brow + row) * K + (k0 + col);
            const __bf16* gb = B + (size_t)(bcol + row) * K + (k0 + col);
            GLOAD16(ga, &As[(q * 256 + wv * 64) * 8]);
            GLOAD16(gb, &Bs[(q * 256 + wv * 64) * 8]);
        }
        __syncthreads();

#pragma unroll
        for (int ks = 0; ks < 2; ++ks) {
            bf16x8 af[4], bfr[4];
#pragma unroll
            for (int r = 0; r < 4; ++r) {
                int arow = wm * 64 + r * 16 + l16;
                af[r] = *(const bf16x8*)&As[arow * 64 + (((ks * 4 + quad) ^ (arow & 7)) << 3)];
                int brw = wn * 64 + r * 16 + l16;
                bfr[r] = *(const bf16x8*)&Bs[brw * 64 + (((ks * 4 + quad) ^ (brw & 7)) << 3)];
            }
#pragma unroll
            for (int r = 0; r < 4; ++r)
#pragma unroll
                for (int c = 0; c < 4; ++c)
                    acc[r][c] = __builtin_amdgcn_mfma_f32_16x16x32_bf16(af[r], bfr[c], acc[r][c], 0, 0, 0);
        }
        __syncthreads();
    }

    float* Cz = Cpart + (size_t)z * MN;
#pragma unroll
    for (int r = 0; r < 4; ++r)
#pragma unroll
        for (int c = 0; c < 4; ++c)
#pragma unroll
            for (int g = 0; g < 4; ++g) {
                int grow = brow + wm * 64 + r * 16 + quad * 4 + g;
                int gcol = bcol + wn * 64 + c * 16 + l16;
                Cz[(size_t)grow * N + gcol] = acc[r][c][g];
            }
}

// ---------------- kernel 5: final reduce (float4) ----------------
__global__ __launch_bounds__(256) void reduce_kernel(const float* __restrict__ part,
                                                     int S, float* __restrict__ out)
{
    int i = blockIdx.x * 256 + threadIdx.x;          // float4 index, < 524288
    const float4* p4 = (const float4*)part;
    float4 s = p4[i];
    for (int z = 1; z < S; ++z) {
        float4 v = p4[(size_t)z * (MN / 4) + i];
        s.x += v.x; s.y += v.y; s.z += v.z; s.w += v.w;
    }
    ((float4*)out)[i] = s;
}

// ---------------- launch ----------------
extern "C" void kernel_launch(void* const* d_in, const int* in_sizes, int n_in,
                              void* d_out, int out_size, void* d_ws, size_t ws_size,
                              hipStream_t stream)
{
    const float* x    = (const float*)d_in[0];
    const float* emb0 = (const float*)d_in[1];
    const float* w1_0 = (const float*)d_in[2];
    const float* b1_0 = (const float*)d_in[3];
    const float* w2_0 = (const float*)d_in[4];
    const float* b2_0 = (const float*)d_in[5];
    const float* emb1 = (const float*)d_in[6];
    const float* w1_1 = (const float*)d_in[7];
    const float* b1_1 = (const float*)d_in[8];
    const float* w2_1 = (const float*)d_in[9];
    const float* b2_1 = (const float*)d_in[10];

    char* ws = (char*)d_ws;
    const size_t PHI_OFF  = 0;                       // 37,748,736 (bf16 phi, reused)
    const size_t BW0_OFF  = 37748736;                //  4,718,592
    const size_t BW1_OFF  = BW0_OFF + 4718592;
    const size_t MC_OFF   = BW1_OFF + 4718592;       //  8,192 (2 x 1024 floats)
    const size_t PART_OFF = MC_OFF + 8192;           //  S x 8,388,608

    // adaptive split-K: S must divide 72 (K/BK); pick largest that fits ws
    int S = 1;
    const size_t SLAB = 8388608ull;
    if      (ws_size >= PART_OFF + 8 * SLAB) S = 8;
    else if (ws_size >= PART_OFF + 6 * SLAB) S = 6;
    else if (ws_size >= PART_OFF + 4 * SLAB) S = 4;
    else if (ws_size >= PART_OFF + 3 * SLAB) S = 3;
    else if (ws_size >= PART_OFF + 2 * SLAB) S = 2;
    int ksz = KDIM / S;

    u16*   phi  = (u16*)(ws + PHI_OFF);
    u16*   Bw0  = (u16*)(ws + BW0_OFF);
    u16*   Bw1  = (u16*)(ws + BW1_OFF);
    float* Mc   = (float*)(ws + MC_OFF);
    float* part = (float*)(ws + PART_OFF);

    // weight generation (both layers)
    meff_kernel<<<293, 256, 0, stream>>>(w1_0, b1_0, w2_0, b2_0,
                                         w1_1, b1_1, w2_1, b2_1, Mc);
    genw_kernel<<<dim3(256, 2), 256, 0, stream>>>(emb0, emb1, Mc, Bw0, Bw1);

    // layer 0
    phi_kernel<<<8192, 256, 0, stream>>>(x, nullptr, 0, phi);
    gemm_kernel<<<dim3(32, 4, S), 256, 0, stream>>>((const __bf16*)phi, (const __bf16*)Bw0,
                                                    part, OUTF, KDIM, ksz);
    // layer 1 (phi fuses the split-K reduce of layer-0 partials)
    phi_kernel<<<8192, 256, 0, stream>>>(nullptr, part, S, phi);
    gemm_kernel<<<dim3(32, 4, S), 256, 0, stream>>>((const __bf16*)phi, (const __bf16*)Bw1,
                                                    part, OUTF, KDIM, ksz);
    reduce_kernel<<<2048, 256, 0, stream>>>(part, S, (float*)d_out);
}

// Round 5
// 315.288 us; speedup vs baseline: 1.2309x; 1.2309x over previous
//
#include <hip/hip_runtime.h>
#include <cstdint>
#include <cstddef>

typedef unsigned short u16;
typedef unsigned int   u32;

typedef __bf16 bf16x8 __attribute__((ext_vector_type(8)));
typedef float  f32x4  __attribute__((ext_vector_type(4)));

#define NROWS 4096
#define INF   512
#define OUTF  512
#define EMB   64
#define MHID  128
#define DB    9
#define KDIM  (INF * DB)   /* 4608 */
#define MN    (NROWS * OUTF)   /* 2097152 */

__device__ __forceinline__ u16 f2bf(float f) {
    union { float f; u32 ui; } v; v.f = f;
    u32 u = v.ui;
    u += 0x7fffu + ((u >> 16) & 1u);   // RTNE
    return (u16)(u >> 16);
}
__device__ __forceinline__ float gridv(int t) { return (float)(t - 3) * 0.4f - 1.0f; }

// ---------------- kernel 1: meff — one wave per output ----------------
__global__ __launch_bounds__(256) void meff_kernel(
    const float* __restrict__ w1_0, const float* __restrict__ b1_0,
    const float* __restrict__ w2_0, const float* __restrict__ b2_0,
    const float* __restrict__ w1_1, const float* __restrict__ b1_1,
    const float* __restrict__ w2_1, const float* __restrict__ b2_1,
    float* __restrict__ Mc)
{
    int tid  = threadIdx.x;
    int lane = tid & 63;
    int wid  = blockIdx.x * 4 + (tid >> 6);
    if (wid >= 1170) return;
    int layer = wid / 585;
    int o     = wid % 585;
    const float* w1 = layer ? w1_1 : w1_0;
    const float* b1 = layer ? b1_1 : b1_0;
    const float* w2 = layer ? w2_1 : w2_0;
    const float* b2 = layer ? b2_1 : b2_0;

    float p;
    int d;
    if (o < 576) {
        int j = o / 9; d = o % 9;
        p = w1[lane * EMB + j]        * w2[d * MHID + lane]
          + w1[(lane + 64) * EMB + j] * w2[d * MHID + lane + 64];
    } else {
        d = o - 576;
        p = b1[lane] * w2[d * MHID + lane] + b1[lane + 64] * w2[d * MHID + lane + 64];
    }
#pragma unroll
    for (int off = 32; off >= 1; off >>= 1)
        p += __shfl_xor(p, off, 64);
    if (lane == 0) {
        if (o >= 576) p += b2[d];
        Mc[layer * 1024 + o] = p;
    }
}

// ---------------- kernel 2: genw v3 — line-burst loads, 4 rows/thread ----------
// Bw[e*9+d] = bf16( emb[e,:]*Meff[:,d] + c[d] ).  grid (256, 2) x 256 thr.
// Each thread: rows {0,256,512,768}+tid of its 1024-row block. Per half-line:
// burst 8 consecutive float4 per row (full 128B cache line -> MSHR-merged,
// fetched ONCE; fixes R4's 2.36x over-fetch). Ms reads wave-uniform broadcast,
// amortized over 4 rows.
__global__ __launch_bounds__(256) void genw_kernel(
    const float* __restrict__ emb0, const float* __restrict__ emb1,
    const float* __restrict__ Mc,
    u16* __restrict__ Bw0, u16* __restrict__ Bw1)
{
    __shared__ float Ms[64 * 12];                 // 3072 B
    __shared__ float Cs[9];
    __shared__ __align__(16) u16 ob[1024 * 9];    // 18432 B out-stage

    int layer = blockIdx.y;
    const float* emb = layer ? emb1 : emb0;
    u16* Bw = layer ? Bw1 : Bw0;
    const float* mc = Mc + layer * 1024;

    int tid = threadIdx.x;
    for (int idx = tid; idx < 585; idx += 256) {
        float v = mc[idx];
        if (idx < 576) Ms[(idx / 9) * 12 + (idx % 9)] = v;
        else Cs[idx - 576] = v;
    }
    __syncthreads();

    size_t rowbase = (size_t)blockIdx.x * 1024;
    float acc[4][9];
#pragma unroll
    for (int r = 0; r < 4; ++r)
#pragma unroll
        for (int d = 0; d < 9; ++d) acc[r][d] = Cs[d];

    const float4* g4 = (const float4*)(emb + rowbase * EMB);
#pragma unroll
    for (int half = 0; half < 2; ++half) {
        float4 buf[4][8];
#pragma unroll
        for (int r = 0; r < 4; ++r)
#pragma unroll
            for (int q = 0; q < 8; ++q)
                buf[r][q] = g4[(size_t)(r * 256 + tid) * 16 + half * 8 + q];
#pragma unroll
        for (int q = 0; q < 8; ++q) {
#pragma unroll
            for (int t = 0; t < 4; ++t) {
                const float* m = &Ms[(half * 32 + q * 4 + t) * 12];
                float e0 = (t == 0) ? buf[0][q].x : (t == 1) ? buf[0][q].y : (t == 2) ? buf[0][q].z : buf[0][q].w;
                float e1 = (t == 0) ? buf[1][q].x : (t == 1) ? buf[1][q].y : (t == 2) ? buf[1][q].z : buf[1][q].w;
                float e2 = (t == 0) ? buf[2][q].x : (t == 1) ? buf[2][q].y : (t == 2) ? buf[2][q].z : buf[2][q].w;
                float e3 = (t == 0) ? buf[3][q].x : (t == 1) ? buf[3][q].y : (t == 2) ? buf[3][q].z : buf[3][q].w;
#pragma unroll
                for (int d = 0; d < 9; ++d) {
                    float mv = m[d];              // wave-uniform LDS broadcast
                    acc[0][d] += e0 * mv;
                    acc[1][d] += e1 * mv;
                    acc[2][d] += e2 * mv;
                    acc[3][d] += e3 * mv;
                }
            }
        }
    }

#pragma unroll
    for (int r = 0; r < 4; ++r)
#pragma unroll
        for (int d = 0; d < 9; ++d)
            ob[(r * 256 + tid) * 9 + d] = f2bf(acc[r][d]);
    __syncthreads();

    const uint4* src = (const uint4*)ob;          // 1152 uint4
    uint4* dst = (uint4*)(Bw + rowbase * 9);
    for (int s = tid; s < 1152; s += 256) dst[s] = src[s];
}

// ---------------- kernel 3: phi — div-free spline + silu ----------------
__global__ __launch_bounds__(256) void phi_kernel(const float* __restrict__ xin,
                                                  const float* __restrict__ part,
                                                  int S,
                                                  u16* __restrict__ phi)
{
    __shared__ __align__(16) u16 lbuf[256 * 9];   // 4608 B
    int tid = threadIdx.x;
    int idx = blockIdx.x * 256 + tid;

    float xv;
    if (part) {
        xv = 0.f;
        for (int z = 0; z < S; ++z) xv += part[(size_t)z * MN + idx];
    } else {
        xv = xin[idx];
    }

    float b[11];
#pragma unroll
    for (int t = 0; t < 11; ++t)
        b[t] = (xv >= gridv(t) && xv < gridv(t + 1)) ? 1.0f : 0.0f;
#pragma unroll
    for (int k = 1; k <= 3; ++k) {
#pragma unroll
        for (int t = 0; t + k < 11; ++t) {
            // constants after unroll: 1/C folds at compile time (no v_div)
            float rdp = 1.0f / ((gridv(t + k) - gridv(t)) + 1e-8f);
            float rdn = 1.0f / ((gridv(t + k + 1) - gridv(t + 1)) + 1e-8f);
            b[t] = (xv - gridv(t)) * rdp * b[t] + (gridv(t + k + 1) - xv) * rdn * b[t + 1];
        }
    }
    float sil = xv / (1.0f + expf(-xv));          // one real div, keep

#pragma unroll
    for (int d = 0; d < 8; ++d) lbuf[tid * 9 + d] = f2bf(b[d]);
    lbuf[tid * 9 + 8] = f2bf(sil);
    __syncthreads();

    const uint4* src = (const uint4*)lbuf;        // 288 uint4
    uint4* dst = (uint4*)(phi + (size_t)blockIdx.x * 256 * 9);
    for (int s = tid; s < 288; s += 256) dst[s] = src[s];
}

// ---------------- kernel 4: split-K GEMM  Cpart[z] = A[:,kz] * B[:,kz]^T ----------
#define GLOAD16(gp, lp) __builtin_amdgcn_global_load_lds(                         \
    (const __attribute__((address_space(1))) u32*)(gp),                           \
    (__attribute__((address_space(3))) u32*)(lp), 16, 0, 0)

__global__ __launch_bounds__(256, 4) void gemm_kernel(const __bf16* __restrict__ A,
                                                      const __bf16* __restrict__ B,
                                                      float* __restrict__ Cpart,
                                                      int N, int K, int ksz)
{
    __shared__ __align__(16) __bf16 As[128 * 64];
    __shared__ __align__(16) __bf16 Bs[128 * 64];

    int tid  = threadIdx.x;
    int lane = tid & 63;
    int wv   = tid >> 6;
    int wm   = wv >> 1, wn = wv & 1;
    int brow = blockIdx.x * 128;
    int bcol = blockIdx.y * 128;
    int z    = blockIdx.z;
    int kbeg = z * ksz, kend = kbeg + ksz;

    f32x4 acc[4][4];
#pragma unroll
    for (int r = 0; r < 4; ++r)
#pragma unroll
        for (int c = 0; c < 4; ++c)
#pragma unroll
            for (int g = 0; g < 4; ++g) acc[r][c][g] = 0.0f;

    int quad = lane >> 4;
    int l16  = lane & 15;

    for (int k0 = kbeg; k0 < kend; k0 += 64) {
#pragma unroll
        for (int q = 0; q < 4; ++q) {
            int chunk = q * 256 + wv * 64 + lane;
            int row   = chunk >> 3;
            int slot  = chunk & 7;
            int col   = ((slot ^ (row & 7)) << 3);   // XOR swizzle (0 conflicts, R2)
            const __bf16* ga = A + (size_t)(brow + row) * K + (k0 + col);
            const __bf16* gb = B + (size_t)(bcol + row) * K + (k0 + col);
            GLOAD16(ga, &As[(q * 256 + wv * 64) * 8]);
            GLOAD16(gb, &Bs[(q * 256 + wv * 64) * 8]);
        }
        __syncthreads();

#pragma unroll
        for (int ks = 0; ks < 2; ++ks) {
            bf16x8 af[4], bfr[4];
#pragma unroll
            for (int r = 0; r < 4; ++r) {
                int arow = wm * 64 + r * 16 + l16;
                af[r] = *(const bf16x8*)&As[arow * 64 + (((ks * 4 + quad) ^ (arow & 7)) << 3)];
                int brw = wn * 64 + r * 16 + l16;
                bfr[r] = *(const bf16x8*)&Bs[brw * 64 + (((ks * 4 + quad) ^ (brw & 7)) << 3)];
            }
#pragma unroll
            for (int r = 0; r < 4; ++r)
#pragma unroll
                for (int c = 0; c < 4; ++c)
                    acc[r][c] = __builtin_amdgcn_mfma_f32_16x16x32_bf16(af[r], bfr[c], acc[r][c], 0, 0, 0);
        }
        __syncthreads();
    }

    float* Cz = Cpart + (size_t)z * MN;
#pragma unroll
    for (int r = 0; r < 4; ++r)
#pragma unroll
        for (int c = 0; c < 4; ++c)
#pragma unroll
            for (int g = 0; g < 4; ++g) {
                int grow = brow + wm * 64 + r * 16 + quad * 4 + g;
                int gcol = bcol + wn * 64 + c * 16 + l16;
                Cz[(size_t)grow * N + gcol] = acc[r][c][g];
            }
}

// ---------------- kernel 5: final reduce (float4) ----------------
__global__ __launch_bounds__(256) void reduce_kernel(const float* __restrict__ part,
                                                     int S, float* __restrict__ out)
{
    int i = blockIdx.x * 256 + threadIdx.x;
    const float4* p4 = (const float4*)part;
    float4 s = p4[i];
    for (int z = 1; z < S; ++z) {
        float4 v = p4[(size_t)z * (MN / 4) + i];
        s.x += v.x; s.y += v.y; s.z += v.z; s.w += v.w;
    }
    ((float4*)out)[i] = s;
}

// ---------------- launch ----------------
extern "C" void kernel_launch(void* const* d_in, const int* in_sizes, int n_in,
                              void* d_out, int out_size, void* d_ws, size_t ws_size,
                              hipStream_t stream)
{
    const float* x    = (const float*)d_in[0];
    const float* emb0 = (const float*)d_in[1];
    const float* w1_0 = (const float*)d_in[2];
    const float* b1_0 = (const float*)d_in[3];
    const float* w2_0 = (const float*)d_in[4];
    const float* b2_0 = (const float*)d_in[5];
    const float* emb1 = (const float*)d_in[6];
    const float* w1_1 = (const float*)d_in[7];
    const float* b1_1 = (const float*)d_in[8];
    const float* w2_1 = (const float*)d_in[9];
    const float* b2_1 = (const float*)d_in[10];

    char* ws = (char*)d_ws;
    const size_t PHI_OFF  = 0;                       // 37,748,736
    const size_t BW0_OFF  = 37748736;                //  4,718,592
    const size_t BW1_OFF  = BW0_OFF + 4718592;
    const size_t MC_OFF   = BW1_OFF + 4718592;       //  8,192
    const size_t PART_OFF = MC_OFF + 8192;

    // split-K: S=4 (R3 vs R4 A/B: S=8 cost ~+19 us in partial traffic)
    int S = 1;
    const size_t SLAB = 8388608ull;
    if      (ws_size >= PART_OFF + 4 * SLAB) S = 4;
    else if (ws_size >= PART_OFF + 2 * SLAB) S = 2;
    int ksz = KDIM / S;

    u16*   phi  = (u16*)(ws + PHI_OFF);
    u16*   Bw0  = (u16*)(ws + BW0_OFF);
    u16*   Bw1  = (u16*)(ws + BW1_OFF);
    float* Mc   = (float*)(ws + MC_OFF);
    float* part = (float*)(ws + PART_OFF);

    meff_kernel<<<293, 256, 0, stream>>>(w1_0, b1_0, w2_0, b2_0,
                                         w1_1, b1_1, w2_1, b2_1, Mc);
    genw_kernel<<<dim3(256, 2), 256, 0, stream>>>(emb0, emb1, Mc, Bw0, Bw1);

    phi_kernel<<<8192, 256, 0, stream>>>(x, nullptr, 0, phi);
    gemm_kernel<<<dim3(32, 4, S), 256, 0, stream>>>((const __bf16*)phi, (const __bf16*)Bw0,
                                                    part, OUTF, KDIM, ksz);
    phi_kernel<<<8192, 256, 0, stream>>>(nullptr, part, S, phi);
    gemm_kernel<<<dim3(32, 4, S), 256, 0, stream>>>((const __bf16*)phi, (const __bf16*)Bw1,
                                                    part, OUTF, KDIM, ksz);
    reduce_kernel<<<2048, 256, 0, stream>>>(part, S, (float*)d_out);
}

// Round 7
// 271.317 us; speedup vs baseline: 1.4303x; 1.1621x over previous
//
#include <hip/hip_runtime.h>
#include <cstdint>
#include <cstddef>

typedef unsigned short u16;
typedef unsigned int   u32;

typedef __bf16 bf16x8 __attribute__((ext_vector_type(8)));
typedef float  f32x4  __attribute__((ext_vector_type(4)));

#define NROWS 4096
#define INF   512
#define OUTF  512
#define EMB   64
#define MHID  128
#define DB    9
#define KDIM  (INF * DB)   /* 4608 */
#define MN    (NROWS * OUTF)   /* 2097152 */

__device__ __forceinline__ u16 f2bf(float f) {
    union { float f; u32 ui; } v; v.f = f;
    u32 u = v.ui;
    u += 0x7fffu + ((u >> 16) & 1u);   // RTNE
    return (u16)(u >> 16);
}
__device__ __forceinline__ float gridv(int t) { return (float)(t - 3) * 0.4f - 1.0f; }

// ---------------- kernel 1: meff — one wave per output ----------------
__global__ __launch_bounds__(256) void meff_kernel(
    const float* __restrict__ w1_0, const float* __restrict__ b1_0,
    const float* __restrict__ w2_0, const float* __restrict__ b2_0,
    const float* __restrict__ w1_1, const float* __restrict__ b1_1,
    const float* __restrict__ w2_1, const float* __restrict__ b2_1,
    float* __restrict__ Mc)
{
    int tid  = threadIdx.x;
    int lane = tid & 63;
    int wid  = blockIdx.x * 4 + (tid >> 6);
    if (wid >= 1170) return;
    int layer = wid / 585;
    int o     = wid % 585;
    const float* w1 = layer ? w1_1 : w1_0;
    const float* b1 = layer ? b1_1 : b1_0;
    const float* w2 = layer ? w2_1 : w2_0;
    const float* b2 = layer ? b2_1 : b2_0;

    float p;
    int d;
    if (o < 576) {
        int j = o / 9; d = o % 9;
        p = w1[lane * EMB + j]        * w2[d * MHID + lane]
          + w1[(lane + 64) * EMB + j] * w2[d * MHID + lane + 64];
    } else {
        d = o - 576;
        p = b1[lane] * w2[d * MHID + lane] + b1[lane + 64] * w2[d * MHID + lane + 64];
    }
#pragma unroll
    for (int off = 32; off >= 1; off >>= 1)
        p += __shfl_xor(p, off, 64);
    if (lane == 0) {
        if (o >= 576) p += b2[d];
        Mc[layer * 1024 + o] = p;
    }
}

// ---------------- kernel 2: genw v5 — R3-proven staging + SGPR Meff ----------
// Identical structure to the R3 correct kernel (FETCH was clean: 65.6MB ==
// ideal) except Ms/Cs move from LDS to direct wave-uniform mc[] reads with
// compile-time indices -> s_load/SGPR operands in v_fmac. Removes the 576
// ds_read_b32 per row-sweep that made R3 LDS-issue-bound.
__global__ __launch_bounds__(256) void genw_kernel(
    const float* __restrict__ emb0, const float* __restrict__ emb1,
    const float* __restrict__ Mc,
    u16* __restrict__ Bw0, u16* __restrict__ Bw1)
{
    __shared__ __align__(16) float tile[256 * 65];   // 66560 B, pad-65 rows
    int layer = blockIdx.y;
    const float* emb = layer ? emb1 : emb0;
    u16* Bw = layer ? Bw1 : Bw0;
    const float* mc = Mc + layer * 1024;

    int tid = threadIdx.x;

    // stage 256 rows x 64 cols, coalesced float4 (proven clean-fetch in R3)
    size_t rowbase = (size_t)blockIdx.x * 256;
    const float4* g4 = (const float4*)(emb + rowbase * EMB);
#pragma unroll
    for (int it = 0; it < 16; ++it) {
        int f = it * 256 + tid;          // 0..4095
        float4 v = g4[f];
        int row = f >> 4, c4 = (f & 15) * 4;
        float* t = &tile[row * 65 + c4];
        t[0] = v.x; t[1] = v.y; t[2] = v.z; t[3] = v.w;
    }
    __syncthreads();

    float acc[9];
#pragma unroll
    for (int d = 0; d < 9; ++d) acc[d] = mc[576 + d];    // c[d] (uniform)

    const float* myrow = &tile[tid * 65];
#pragma unroll
    for (int jj = 0; jj < 16; ++jj) {
        float v0 = myrow[jj * 4 + 0];
        float v1 = myrow[jj * 4 + 1];
        float v2 = myrow[jj * 4 + 2];
        float v3 = myrow[jj * 4 + 3];
#pragma unroll
        for (int d = 0; d < 9; ++d)
            acc[d] += v0 * mc[(jj * 4 + 0) * 9 + d]      // uniform -> SGPR
                    + v1 * mc[(jj * 4 + 1) * 9 + d]
                    + v2 * mc[(jj * 4 + 2) * 9 + d]
                    + v3 * mc[(jj * 4 + 3) * 9 + d];
    }

    __syncthreads();                     // done reading tile
    u16* ob = (u16*)tile;                // reuse as 256*9 u16 out-stage
#pragma unroll
    for (int d = 0; d < 9; ++d) ob[tid * 9 + d] = f2bf(acc[d]);
    __syncthreads();

    const uint4* src = (const uint4*)ob;             // 288 uint4
    uint4* dst = (uint4*)(Bw + rowbase * 9);         // blk*4608 B, 16B aligned
    for (int s = tid; s < 288; s += 256) dst[s] = src[s];
}

// ---------------- kernel 3: phi — div-free spline + silu ----------------
__global__ __launch_bounds__(256) void phi_kernel(const float* __restrict__ xin,
                                                  const float* __restrict__ part,
                                                  int S,
                                                  u16* __restrict__ phi)
{
    __shared__ __align__(16) u16 lbuf[256 * 9];   // 4608 B
    int tid = threadIdx.x;
    int idx = blockIdx.x * 256 + tid;

    float xv;
    if (part) {
        xv = 0.f;
        for (int z = 0; z < S; ++z) xv += part[(size_t)z * MN + idx];
    } else {
        xv = xin[idx];
    }

    float b[11];
#pragma unroll
    for (int t = 0; t < 11; ++t)
        b[t] = (xv >= gridv(t) && xv < gridv(t + 1)) ? 1.0f : 0.0f;
#pragma unroll
    for (int k = 1; k <= 3; ++k) {
#pragma unroll
        for (int t = 0; t + k < 11; ++t) {
            float rdp = 1.0f / ((gridv(t + k) - gridv(t)) + 1e-8f);
            float rdn = 1.0f / ((gridv(t + k + 1) - gridv(t + 1)) + 1e-8f);
            b[t] = (xv - gridv(t)) * rdp * b[t] + (gridv(t + k + 1) - xv) * rdn * b[t + 1];
        }
    }
    float sil = xv / (1.0f + expf(-xv));

#pragma unroll
    for (int d = 0; d < 8; ++d) lbuf[tid * 9 + d] = f2bf(b[d]);
    lbuf[tid * 9 + 8] = f2bf(sil);
    __syncthreads();

    const uint4* src = (const uint4*)lbuf;        // 288 uint4
    uint4* dst = (uint4*)(phi + (size_t)blockIdx.x * 256 * 9);
    for (int s = tid; s < 288; s += 256) dst[s] = src[s];
}

// ---------------- kernel 4: split-K GEMM  Cpart[z] = A[:,kz] * B[:,kz]^T ----------
#define GLOAD16(gp, lp) __builtin_amdgcn_global_load_lds(                         \
    (const __attribute__((address_space(1))) u32*)(gp),                           \
    (__attribute__((address_space(3))) u32*)(lp), 16, 0, 0)

__global__ __launch_bounds__(256, 4) void gemm_kernel(const __bf16* __restrict__ A,
                                                      const __bf16* __restrict__ B,
                                                      float* __restrict__ Cpart,
                                                      int N, int K, int ksz)
{
    __shared__ __align__(16) __bf16 As[128 * 64];
    __shared__ __align__(16) __bf16 Bs[128 * 64];

    int tid  = threadIdx.x;
    int lane = tid & 63;
    int wv   = tid >> 6;
    int wm   = wv >> 1, wn = wv & 1;
    int brow = blockIdx.x * 128;
    int bcol = blockIdx.y * 128;
    int z    = blockIdx.z;
    int kbeg = z * ksz, kend = kbeg + ksz;

    f32x4 acc[4][4];
#pragma unroll
    for (int r = 0; r < 4; ++r)
#pragma unroll
        for (int c = 0; c < 4; ++c)
#pragma unroll
            for (int g = 0; g < 4; ++g) acc[r][c][g] = 0.0f;

    int quad = lane >> 4;
    int l16  = lane & 15;

    for (int k0 = kbeg; k0 < kend; k0 += 64) {
#pragma unroll
        for (int q = 0; q < 4; ++q) {
            int chunk = q * 256 + wv * 64 + lane;
            int row   = chunk >> 3;
            int slot  = chunk & 7;
            int col   = ((slot ^ (row & 7)) << 3);   // XOR swizzle (0 conflicts, R2)
            const __bf16* ga = A + (size_t)(brow + row) * K + (k0 + col);
            const __bf16* gb = B + (size_t)(bcol + row) * K + (k0 + col);
            GLOAD16(ga, &As[(q * 256 + wv * 64) * 8]);
            GLOAD16(gb, &Bs[(q * 256 + wv * 64) * 8]);
        }
        __syncthreads();

#pragma unroll
        for (int ks = 0; ks < 2; ++ks) {
            bf16x8 af[4], bfr[4];
#pragma unroll
            for (int r = 0; r < 4; ++r) {
                int arow = wm * 64 + r * 16 + l16;
                af[r] = *(const bf16x8*)&As[arow * 64 + (((ks * 4 + quad) ^ (arow & 7)) << 3)];
                int brw = wn * 64 + r * 16 + l16;
                bfr[r] = *(const bf16x8*)&Bs[brw * 64 + (((ks * 4 + quad) ^ (brw & 7)) << 3)];
            }
#pragma unroll
            for (int r = 0; r < 4; ++r)
#pragma unroll
                for (int c = 0; c < 4; ++c)
                    acc[r][c] = __builtin_amdgcn_mfma_f32_16x16x32_bf16(af[r], bfr[c], acc[r][c], 0, 0, 0);
        }
        __syncthreads();
    }

    float* Cz = Cpart + (size_t)z * MN;
#pragma unroll
    for (int r = 0; r < 4; ++r)
#pragma unroll
        for (int c = 0; c < 4; ++c)
#pragma unroll
            for (int g = 0; g < 4; ++g) {
                int grow = brow + wm * 64 + r * 16 + quad * 4 + g;
                int gcol = bcol + wn * 64 + c * 16 + l16;
                Cz[(size_t)grow * N + gcol] = acc[r][c][g];
            }
}

// ---------------- kernel 5: final reduce (float4) ----------------
__global__ __launch_bounds__(256) void reduce_kernel(const float* __restrict__ part,
                                                     int S, float* __restrict__ out)
{
    int i = blockIdx.x * 256 + threadIdx.x;
    const float4* p4 = (const float4*)part;
    float4 s = p4[i];
    for (int z = 1; z < S; ++z) {
        float4 v = p4[(size_t)z * (MN / 4) + i];
        s.x += v.x; s.y += v.y; s.z += v.z; s.w += v.w;
    }
    ((float4*)out)[i] = s;
}

// ---------------- launch ----------------
extern "C" void kernel_launch(void* const* d_in, const int* in_sizes, int n_in,
                              void* d_out, int out_size, void* d_ws, size_t ws_size,
                              hipStream_t stream)
{
    const float* x    = (const float*)d_in[0];
    const float* emb0 = (const float*)d_in[1];
    const float* w1_0 = (const float*)d_in[2];
    const float* b1_0 = (const float*)d_in[3];
    const float* w2_0 = (const float*)d_in[4];
    const float* b2_0 = (const float*)d_in[5];
    const float* emb1 = (const float*)d_in[6];
    const float* w1_1 = (const float*)d_in[7];
    const float* b1_1 = (const float*)d_in[8];
    const float* w2_1 = (const float*)d_in[9];
    const float* b2_1 = (const float*)d_in[10];

    char* ws = (char*)d_ws;
    const size_t PHI_OFF  = 0;                       // 37,748,736
    const size_t BW0_OFF  = 37748736;                //  4,718,592
    const size_t BW1_OFF  = BW0_OFF + 4718592;
    const size_t MC_OFF   = BW1_OFF + 4718592;       //  8,192
    const size_t PART_OFF = MC_OFF + 8192;

    // split-K: S=4 (R3 vs R4 A/B: S=8 cost ~+19 us in partial traffic)
    int S = 1;
    const size_t SLAB = 8388608ull;
    if      (ws_size >= PART_OFF + 4 * SLAB) S = 4;
    else if (ws_size >= PART_OFF + 2 * SLAB) S = 2;
    int ksz = KDIM / S;

    u16*   phi  = (u16*)(ws + PHI_OFF);
    u16*   Bw0  = (u16*)(ws + BW0_OFF);
    u16*   Bw1  = (u16*)(ws + BW1_OFF);
    float* Mc   = (float*)(ws + MC_OFF);
    float* part = (float*)(ws + PART_OFF);

    meff_kernel<<<293, 256, 0, stream>>>(w1_0, b1_0, w2_0, b2_0,
                                         w1_1, b1_1, w2_1, b2_1, Mc);
    genw_kernel<<<dim3(1024, 2), 256, 0, stream>>>(emb0, emb1, Mc, Bw0, Bw1);

    phi_kernel<<<8192, 256, 0, stream>>>(x, nullptr, 0, phi);
    gemm_kernel<<<dim3(32, 4, S), 256, 0, stream>>>((const __bf16*)phi, (const __bf16*)Bw0,
                                                    part, OUTF, KDIM, ksz);
    phi_kernel<<<8192, 256, 0, stream>>>(nullptr, part, S, phi);
    gemm_kernel<<<dim3(32, 4, S), 256, 0, stream>>>((const __bf16*)phi, (const __bf16*)Bw1,
                                                    part, OUTF, KDIM, ksz);
    reduce_kernel<<<2048, 256, 0, stream>>>(part, S, (float*)d_out);
}